// Round 4
// baseline (1787.160 us; speedup 1.0000x reference)
//
#include <hip/hip_runtime.h>
#include <hip/hip_bf16.h>

typedef __hip_bfloat16 bf16;

#define NPIX 65536   // 256*256

__device__ __forceinline__ float b2f(bf16 v) { return __bfloat162float(v); }
__device__ __forceinline__ bf16 f2b(float v) { return __float2bfloat16(v); }
__device__ __forceinline__ float gelu_f(float v) {
  return 0.5f * v * (1.f + erff(v * 0.7071067811865476f));
}

// ---- workspace layout (bytes) — total ~24.1 MiB ----
#define OFF_QKV 0u            // bf16 [192, NPIX] per-batch staging = 25,165,824 B
                              //   planes 0..63 = q (later h1), 64..127 = k (later h2),
                              //   128..191 = v (later o)
#define OFF_KV  25165824u     // fp32 [2,8,72,8] = 36,864 B
#define OFF_KS  25202688u     // fp32 [2,8,72]   =  4,608 B

__global__ void k_zero(float* __restrict__ p, int n) {
  int i = blockIdx.x * 256 + threadIdx.x;
  if (i < n) p[i] = 0.f;
}

// qkv 1x1 conv + ReLU on q,k. Grid (256, 3): y selects q/k/v section. Thread = pixel.
__global__ __launch_bounds__(256) void k_qkv(const float* __restrict__ x,
                                             const float* __restrict__ qkv_w,
                                             const float* __restrict__ qkv_b,
                                             bf16* __restrict__ qkv, int b) {
  int n = blockIdx.x * 256 + threadIdx.x;
  int sec = blockIdx.y;                      // 0=q, 1=k, 2=v
  const float* xp = x + ((size_t)b << 22) + n;
  float xv[64];
#pragma unroll
  for (int ci = 0; ci < 64; ++ci) xv[ci] = xp[(size_t)ci << 16];
  const float* w = qkv_w + sec * 64 * 64;    // [64][64] slice
  const float* bias = qkv_b + sec * 64;
  bf16* op = qkv + ((size_t)(sec * 64) << 16) + n;
  for (int co = 0; co < 64; ++co) {
    float acc = bias[co];
    const float* wr = w + co * 64;
#pragma unroll
    for (int ci = 0; ci < 64; ++ci) acc = fmaf(xv[ci], wr[ci], acc);
    if (sec < 2) acc = fmaxf(acc, 0.f);
    op[(size_t)co << 16] = f2b(acc);
  }
}

// Attention stats: kv[b,h,d,e], ksum[b,h,d].  d = c*9+p, spatial offset (p/3-1, p%3-1).
// Grid 256 = (chunk 32) x (h 8); 576 threads, thread owns one (d,e).
__global__ __launch_bounds__(576) void k_stats(const bf16* __restrict__ qkv,
                                               float* __restrict__ kv,
                                               float* __restrict__ ksum, int b) {
  int tid = threadIdx.x;
  int d = tid >> 3, e = tid & 7;
  int c = d / 9, p = d - c * 9;
  int di = p / 3 - 1, dj = (p % 3) - 1;
  int blk = blockIdx.x;
  int chunk = blk & 31, h = blk >> 5;
  const bf16* kp = qkv + ((size_t)(64 + h * 8 + c) << 16);
  const bf16* vp = qkv + ((size_t)(128 + h * 8 + e) << 16);
  float acc = 0.f, accs = 0.f;
  int n0 = chunk << 11;
  for (int n = n0; n < n0 + 2048; ++n) {
    int y = n >> 8, xx = n & 255;
    int yy = y + di, xc = xx + dj;
    float kval = 0.f;
    if ((unsigned)yy < 256u && (unsigned)xc < 256u) kval = b2f(kp[yy * 256 + xc]);
    float vval = b2f(vp[n]);
    acc = fmaf(kval, vval, acc);
    accs += kval;
  }
  atomicAdd(&kv[(((b * 8 + h) * 72 + d) << 3) + e], acc);
  if (e == 0) atomicAdd(&ksum[(b * 8 + h) * 72 + d], accs);
}

// o[h*8+e, n] = (sum_d q[n,d]*kv[d,e]) / (sum_d q[n,d]*ksum[d] + eps); o -> v planes.
// Grid 2048 = (chunk 256) x (h 8); thread = pixel.
__global__ __launch_bounds__(256) void k_apply(bf16* __restrict__ qkv,
                                               const float* __restrict__ kv,
                                               const float* __restrict__ ksum, int b) {
  int blk = blockIdx.x;
  int chunk = blk & 255, h = blk >> 8;
  int n = (chunk << 8) + threadIdx.x;
  int y = n >> 8, xx = n & 255;
  const float* kvb = kv + (size_t)((b * 8 + h) * 72) * 8;
  const float* ksb = ksum + (b * 8 + h) * 72;
  float num[8] = {0.f, 0.f, 0.f, 0.f, 0.f, 0.f, 0.f, 0.f};
  float den = 0.f;
  for (int c = 0; c < 8; ++c) {
    const bf16* qp = qkv + ((size_t)(h * 8 + c) << 16);
#pragma unroll
    for (int p = 0; p < 9; ++p) {
      int yy = y + p / 3 - 1, xc = xx + p % 3 - 1;
      float qv = 0.f;
      if ((unsigned)yy < 256u && (unsigned)xc < 256u) qv = b2f(qp[yy * 256 + xc]);
      int d = c * 9 + p;
      den = fmaf(qv, ksb[d], den);
#pragma unroll
      for (int e = 0; e < 8; ++e) num[e] = fmaf(qv, kvb[d * 8 + e], num[e]);
    }
  }
  float inv = 1.f / (den + 1e-6f);
#pragma unroll
  for (int e = 0; e < 8; ++e)
    qkv[((size_t)(128 + h * 8 + e) << 16) + n] = f2b(num[e] * inv);
}

// proj 3x3 conv + residual(x) -> x1 stored in d_out (fp32). o in v planes.
// Grid 4096 = (y 256) x (co-group 16 of 4); thread = x.
__global__ __launch_bounds__(256) void k_proj(const bf16* __restrict__ qkv,
                                              const float* __restrict__ proj_w,
                                              const float* __restrict__ proj_b,
                                              const float* __restrict__ x,
                                              float* __restrict__ out, int b) {
  int blk = blockIdx.x;
  int y = blk & 255, g = blk >> 8;
  int co0 = g * 4;
  int xx = threadIdx.x;
  float a0 = proj_b[co0], a1 = proj_b[co0 + 1], a2 = proj_b[co0 + 2], a3 = proj_b[co0 + 3];
  for (int ci = 0; ci < 64; ++ci) {
    const bf16* ip = qkv + ((size_t)(128 + ci) << 16);
    float iv[9];
#pragma unroll
    for (int p = 0; p < 9; ++p) {
      int yy = y + p / 3 - 1, xc = xx + p % 3 - 1;
      iv[p] = ((unsigned)yy < 256u && (unsigned)xc < 256u) ? b2f(ip[yy * 256 + xc]) : 0.f;
    }
#pragma unroll
    for (int p = 0; p < 9; ++p) {
      a0 = fmaf(iv[p], proj_w[((co0 + 0) * 64 + ci) * 9 + p], a0);
      a1 = fmaf(iv[p], proj_w[((co0 + 1) * 64 + ci) * 9 + p], a1);
      a2 = fmaf(iv[p], proj_w[((co0 + 2) * 64 + ci) * 9 + p], a2);
      a3 = fmaf(iv[p], proj_w[((co0 + 3) * 64 + ci) * 9 + p], a3);
    }
  }
  int n = (y << 8) + xx;
  float acc[4] = {a0, a1, a2, a3};
#pragma unroll
  for (int j = 0; j < 4; ++j) {
    size_t idx = ((size_t)b << 22) + ((size_t)(co0 + j) << 16) + n;
    out[idx] = x[idx] + acc[j];
  }
}

// ffn1: 1x1 conv on x1 (fp32, in d_out) + exact GELU -> h1 in q planes. Thread = pixel.
__global__ __launch_bounds__(256) void k_ffn1(const float* __restrict__ out,
                                              const float* __restrict__ w1,
                                              const float* __restrict__ b1,
                                              bf16* __restrict__ qkv, int b) {
  int n = blockIdx.x * 256 + threadIdx.x;
  float xv[64];
  const float* xp = out + ((size_t)b << 22) + n;
#pragma unroll
  for (int ci = 0; ci < 64; ++ci) xv[ci] = xp[(size_t)ci << 16];
  for (int co = 0; co < 64; ++co) {
    float acc = b1[co];
    const float* wr = w1 + co * 64;
#pragma unroll
    for (int ci = 0; ci < 64; ++ci) acc = fmaf(xv[ci], wr[ci], acc);
    qkv[((size_t)co << 16) + n] = f2b(gelu_f(acc));
  }
}

// depthwise 3x3 + GELU: h1 (q planes) -> h2 (k planes). Thread = element.
__global__ __launch_bounds__(256) void k_dw(bf16* __restrict__ qkv,
                                            const float* __restrict__ dw_w,
                                            const float* __restrict__ dw_b) {
  int gid = blockIdx.x * 256 + threadIdx.x;   // [0, 64*NPIX)
  int n = gid & 65535;
  int c = gid >> 16;
  int y = n >> 8, xx = n & 255;
  const bf16* ip = qkv + ((size_t)c << 16);
  float acc = dw_b[c];
#pragma unroll
  for (int p = 0; p < 9; ++p) {
    int yy = y + p / 3 - 1, xc = xx + p % 3 - 1;
    if ((unsigned)yy < 256u && (unsigned)xc < 256u)
      acc = fmaf(b2f(ip[yy * 256 + xc]), dw_w[c * 9 + p], acc);
  }
  qkv[((size_t)(64 + c) << 16) + n] = f2b(gelu_f(acc));
}

// ffn2: 1x1 conv on h2 (k planes) + residual x1 (d_out, element-wise in place, fp32).
__global__ __launch_bounds__(256) void k_ffn2(const bf16* __restrict__ qkv,
                                              const float* __restrict__ w2,
                                              const float* __restrict__ b2,
                                              float* __restrict__ out, int b) {
  int n = blockIdx.x * 256 + threadIdx.x;
  float xv[64];
  const bf16* xp = qkv + ((size_t)64 << 16) + n;
#pragma unroll
  for (int ci = 0; ci < 64; ++ci) xv[ci] = b2f(xp[(size_t)ci << 16]);
  for (int co = 0; co < 64; ++co) {
    float acc = b2[co];
    const float* wr = w2 + co * 64;
#pragma unroll
    for (int ci = 0; ci < 64; ++ci) acc = fmaf(xv[ci], wr[ci], acc);
    size_t idx = ((size_t)b << 22) + ((size_t)co << 16) + n;
    out[idx] = out[idx] + acc;
  }
}

extern "C" void kernel_launch(void* const* d_in, const int* in_sizes, int n_in,
                              void* d_out, int out_size, void* d_ws, size_t ws_size,
                              hipStream_t stream) {
  const float* x      = (const float*)d_in[0];
  const float* qkv_w  = (const float*)d_in[1];
  const float* qkv_b  = (const float*)d_in[2];
  const float* proj_w = (const float*)d_in[3];
  const float* proj_b = (const float*)d_in[4];
  const float* ffn1_w = (const float*)d_in[5];
  const float* ffn1_b = (const float*)d_in[6];
  const float* dw_w   = (const float*)d_in[7];
  const float* dw_b   = (const float*)d_in[8];
  const float* ffn2_w = (const float*)d_in[9];
  const float* ffn2_b = (const float*)d_in[10];
  float* out = (float*)d_out;

  char* ws = (char*)d_ws;
  bf16*  qkvb = (bf16*)(ws + OFF_QKV);
  float* kvb  = (float*)(ws + OFF_KV);
  float* ksb  = (float*)(ws + OFF_KS);

  k_zero<<<41, 256, 0, stream>>>(kvb, 10368);  // kv (9216) + ksum (1152), contiguous

  for (int b = 0; b < 2; ++b) {
    k_qkv<<<dim3(256, 3), 256, 0, stream>>>(x, qkv_w, qkv_b, qkvb, b);
    k_stats<<<256, 576, 0, stream>>>(qkvb, kvb, ksb, b);
    k_apply<<<2048, 256, 0, stream>>>(qkvb, kvb, ksb, b);
    k_proj<<<4096, 256, 0, stream>>>(qkvb, proj_w, proj_b, x, out, b);
    k_ffn1<<<256, 256, 0, stream>>>(out, ffn1_w, ffn1_b, qkvb, b);
    k_dw<<<16384, 256, 0, stream>>>(qkvb, dw_w, dw_b);
    k_ffn2<<<256, 256, 0, stream>>>(qkvb, ffn2_w, ffn2_b, out, b);
  }
}

// Round 5
// 1176.309 us; speedup vs baseline: 1.5193x; 1.5193x over previous
//
#include <hip/hip_runtime.h>
#include <hip/hip_bf16.h>

typedef __hip_bfloat16 bf16;

#define NPIX 65536   // 256*256

__device__ __forceinline__ float b2f(bf16 v) { return __bfloat162float(v); }
__device__ __forceinline__ bf16 f2b(float v) { return __float2bfloat16(v); }
__device__ __forceinline__ float gelu_f(float v) {
  return 0.5f * v * (1.f + erff(v * 0.7071067811865476f));
}

// ---- workspace layout (bytes) — total ~24.1 MiB ----
#define OFF_QKV 0u            // bf16 [192, NPIX] per-batch staging = 25,165,824 B
                              //   planes 0..63 = q (later h1), 64..127 = k (later h2),
                              //   128..191 = v (later o)
#define OFF_KV  25165824u     // fp32 [2,8,72,8] = 36,864 B
#define OFF_KS  25202688u     // fp32 [2,8,72]   =  4,608 B

__global__ void k_zero(float* __restrict__ p, int n) {
  int i = blockIdx.x * 256 + threadIdx.x;
  if (i < n) p[i] = 0.f;
}

// qkv 1x1 conv + ReLU on q,k. Grid (256, 3): y selects q/k/v section. Thread = pixel.
__global__ __launch_bounds__(256) void k_qkv(const float* __restrict__ x,
                                             const float* __restrict__ qkv_w,
                                             const float* __restrict__ qkv_b,
                                             bf16* __restrict__ qkv, int b) {
  int n = blockIdx.x * 256 + threadIdx.x;
  int sec = blockIdx.y;                      // 0=q, 1=k, 2=v
  const float* xp = x + ((size_t)b << 22) + n;
  float xv[64];
#pragma unroll
  for (int ci = 0; ci < 64; ++ci) xv[ci] = xp[(size_t)ci << 16];
  const float* w = qkv_w + sec * 64 * 64;    // [64][64] slice
  const float* bias = qkv_b + sec * 64;
  bf16* op = qkv + ((size_t)(sec * 64) << 16) + n;
  for (int co = 0; co < 64; ++co) {
    float acc = bias[co];
    const float* wr = w + co * 64;
#pragma unroll
    for (int ci = 0; ci < 64; ++ci) acc = fmaf(xv[ci], wr[ci], acc);
    if (sec < 2) acc = fmaxf(acc, 0.f);
    op[(size_t)co << 16] = f2b(acc);
  }
}

// Attention stats: kv[b,h,d,e] = sum_n k_c(n+off_p) * v_e(n), ksum[b,h,d] = sum_n k.
// Lane = pixel (coalesced); thread accumulates full 9x8 kv tile + 9 ksum in regs.
// Grid: dim3(8 chunks of 8192 px, 8 c, 8 h); 256 threads.
__global__ __launch_bounds__(256) void k_stats(const bf16* __restrict__ qkv,
                                               float* __restrict__ kv,
                                               float* __restrict__ ksum, int b) {
  int tid = threadIdx.x;
  int chunk = blockIdx.x, c = blockIdx.y, h = blockIdx.z;
  const bf16* kp = qkv + ((size_t)(64 + h * 8 + c) << 16);
  const bf16* vbase = qkv + ((size_t)(128 + h * 8) << 16);
  float acc[9][8];
  float accs[9];
#pragma unroll
  for (int p = 0; p < 9; ++p) {
    accs[p] = 0.f;
#pragma unroll
    for (int e = 0; e < 8; ++e) acc[p][e] = 0.f;
  }
  int n0 = (chunk << 13) + tid;
  for (int i = 0; i < 32; ++i) {
    int n = n0 + (i << 8);
    int y = n >> 8, x = n & 255;
    float v[8];
#pragma unroll
    for (int e = 0; e < 8; ++e) v[e] = b2f(vbase[((size_t)e << 16) + n]);
#pragma unroll
    for (int p = 0; p < 9; ++p) {
      int yy = y + p / 3 - 1, xc = x + (p % 3) - 1;
      float kval = 0.f;
      if ((unsigned)yy < 256u && (unsigned)xc < 256u) kval = b2f(kp[yy * 256 + xc]);
      accs[p] += kval;
#pragma unroll
      for (int e = 0; e < 8; ++e) acc[p][e] = fmaf(kval, v[e], acc[p][e]);
    }
  }
  // 64-lane butterfly reduction, then lane 0 commits.
#pragma unroll
  for (int p = 0; p < 9; ++p) {
#pragma unroll
    for (int e = 0; e < 8; ++e)
#pragma unroll
      for (int s = 32; s; s >>= 1) acc[p][e] += __shfl_xor(acc[p][e], s, 64);
#pragma unroll
    for (int s = 32; s; s >>= 1) accs[p] += __shfl_xor(accs[p], s, 64);
  }
  if ((tid & 63) == 0) {
    int dbase = (b * 8 + h) * 72 + c * 9;
#pragma unroll
    for (int p = 0; p < 9; ++p) {
#pragma unroll
      for (int e = 0; e < 8; ++e) atomicAdd(&kv[((dbase + p) << 3) + e], acc[p][e]);
      atomicAdd(&ksum[dbase + p], accs[p]);
    }
  }
}

// o[h*8+e, n] = (sum_d q[n,d]*kv[d,e]) / (sum_d q[n,d]*ksum[d] + eps); o -> v planes.
// Grid 2048 = (chunk 256) x (h 8); thread = pixel.
__global__ __launch_bounds__(256) void k_apply(bf16* __restrict__ qkv,
                                               const float* __restrict__ kv,
                                               const float* __restrict__ ksum, int b) {
  int blk = blockIdx.x;
  int chunk = blk & 255, h = blk >> 8;
  int n = (chunk << 8) + threadIdx.x;
  int y = n >> 8, xx = n & 255;
  const float* kvb = kv + (size_t)((b * 8 + h) * 72) * 8;
  const float* ksb = ksum + (b * 8 + h) * 72;
  float num[8] = {0.f, 0.f, 0.f, 0.f, 0.f, 0.f, 0.f, 0.f};
  float den = 0.f;
  for (int c = 0; c < 8; ++c) {
    const bf16* qp = qkv + ((size_t)(h * 8 + c) << 16);
#pragma unroll
    for (int p = 0; p < 9; ++p) {
      int yy = y + p / 3 - 1, xc = xx + p % 3 - 1;
      float qv = 0.f;
      if ((unsigned)yy < 256u && (unsigned)xc < 256u) qv = b2f(qp[yy * 256 + xc]);
      int d = c * 9 + p;
      den = fmaf(qv, ksb[d], den);
#pragma unroll
      for (int e = 0; e < 8; ++e) num[e] = fmaf(qv, kvb[d * 8 + e], num[e]);
    }
  }
  float inv = 1.f / (den + 1e-6f);
#pragma unroll
  for (int e = 0; e < 8; ++e)
    qkv[((size_t)(128 + h * 8 + e) << 16) + n] = f2b(num[e] * inv);
}

// proj 3x3 conv + residual(x) -> x1 stored in d_out (fp32). o in v planes.
// Grid 4096 = (y 256) x (co-group 16 of 4); thread = x.
__global__ __launch_bounds__(256) void k_proj(const bf16* __restrict__ qkv,
                                              const float* __restrict__ proj_w,
                                              const float* __restrict__ proj_b,
                                              const float* __restrict__ x,
                                              float* __restrict__ out, int b) {
  int blk = blockIdx.x;
  int y = blk & 255, g = blk >> 8;
  int co0 = g * 4;
  int xx = threadIdx.x;
  float a0 = proj_b[co0], a1 = proj_b[co0 + 1], a2 = proj_b[co0 + 2], a3 = proj_b[co0 + 3];
  for (int ci = 0; ci < 64; ++ci) {
    const bf16* ip = qkv + ((size_t)(128 + ci) << 16);
    float iv[9];
#pragma unroll
    for (int p = 0; p < 9; ++p) {
      int yy = y + p / 3 - 1, xc = xx + p % 3 - 1;
      iv[p] = ((unsigned)yy < 256u && (unsigned)xc < 256u) ? b2f(ip[yy * 256 + xc]) : 0.f;
    }
#pragma unroll
    for (int p = 0; p < 9; ++p) {
      a0 = fmaf(iv[p], proj_w[((co0 + 0) * 64 + ci) * 9 + p], a0);
      a1 = fmaf(iv[p], proj_w[((co0 + 1) * 64 + ci) * 9 + p], a1);
      a2 = fmaf(iv[p], proj_w[((co0 + 2) * 64 + ci) * 9 + p], a2);
      a3 = fmaf(iv[p], proj_w[((co0 + 3) * 64 + ci) * 9 + p], a3);
    }
  }
  int n = (y << 8) + xx;
  float acc[4] = {a0, a1, a2, a3};
#pragma unroll
  for (int j = 0; j < 4; ++j) {
    size_t idx = ((size_t)b << 22) + ((size_t)(co0 + j) << 16) + n;
    out[idx] = x[idx] + acc[j];
  }
}

// ffn1: 1x1 conv on x1 (fp32, in d_out) + exact GELU -> h1 in q planes. Thread = pixel.
__global__ __launch_bounds__(256) void k_ffn1(const float* __restrict__ out,
                                              const float* __restrict__ w1,
                                              const float* __restrict__ b1,
                                              bf16* __restrict__ qkv, int b) {
  int n = blockIdx.x * 256 + threadIdx.x;
  float xv[64];
  const float* xp = out + ((size_t)b << 22) + n;
#pragma unroll
  for (int ci = 0; ci < 64; ++ci) xv[ci] = xp[(size_t)ci << 16];
  for (int co = 0; co < 64; ++co) {
    float acc = b1[co];
    const float* wr = w1 + co * 64;
#pragma unroll
    for (int ci = 0; ci < 64; ++ci) acc = fmaf(xv[ci], wr[ci], acc);
    qkv[((size_t)co << 16) + n] = f2b(gelu_f(acc));
  }
}

// depthwise 3x3 + GELU: h1 (q planes) -> h2 (k planes). Thread = element.
__global__ __launch_bounds__(256) void k_dw(bf16* __restrict__ qkv,
                                            const float* __restrict__ dw_w,
                                            const float* __restrict__ dw_b) {
  int gid = blockIdx.x * 256 + threadIdx.x;   // [0, 64*NPIX)
  int n = gid & 65535;
  int c = gid >> 16;
  int y = n >> 8, xx = n & 255;
  const bf16* ip = qkv + ((size_t)c << 16);
  float acc = dw_b[c];
#pragma unroll
  for (int p = 0; p < 9; ++p) {
    int yy = y + p / 3 - 1, xc = xx + p % 3 - 1;
    if ((unsigned)yy < 256u && (unsigned)xc < 256u)
      acc = fmaf(b2f(ip[yy * 256 + xc]), dw_w[c * 9 + p], acc);
  }
  qkv[((size_t)(64 + c) << 16) + n] = f2b(gelu_f(acc));
}

// ffn2: 1x1 conv on h2 (k planes) + residual x1 (d_out, element-wise in place, fp32).
__global__ __launch_bounds__(256) void k_ffn2(const bf16* __restrict__ qkv,
                                              const float* __restrict__ w2,
                                              const float* __restrict__ b2,
                                              float* __restrict__ out, int b) {
  int n = blockIdx.x * 256 + threadIdx.x;
  float xv[64];
  const bf16* xp = qkv + ((size_t)64 << 16) + n;
#pragma unroll
  for (int ci = 0; ci < 64; ++ci) xv[ci] = b2f(xp[(size_t)ci << 16]);
  for (int co = 0; co < 64; ++co) {
    float acc = b2[co];
    const float* wr = w2 + co * 64;
#pragma unroll
    for (int ci = 0; ci < 64; ++ci) acc = fmaf(xv[ci], wr[ci], acc);
    size_t idx = ((size_t)b << 22) + ((size_t)co << 16) + n;
    out[idx] = out[idx] + acc;
  }
}

extern "C" void kernel_launch(void* const* d_in, const int* in_sizes, int n_in,
                              void* d_out, int out_size, void* d_ws, size_t ws_size,
                              hipStream_t stream) {
  const float* x      = (const float*)d_in[0];
  const float* qkv_w  = (const float*)d_in[1];
  const float* qkv_b  = (const float*)d_in[2];
  const float* proj_w = (const float*)d_in[3];
  const float* proj_b = (const float*)d_in[4];
  const float* ffn1_w = (const float*)d_in[5];
  const float* ffn1_b = (const float*)d_in[6];
  const float* dw_w   = (const float*)d_in[7];
  const float* dw_b   = (const float*)d_in[8];
  const float* ffn2_w = (const float*)d_in[9];
  const float* ffn2_b = (const float*)d_in[10];
  float* out = (float*)d_out;

  char* ws = (char*)d_ws;
  bf16*  qkvb = (bf16*)(ws + OFF_QKV);
  float* kvb  = (float*)(ws + OFF_KV);
  float* ksb  = (float*)(ws + OFF_KS);

  k_zero<<<41, 256, 0, stream>>>(kvb, 10368);  // kv (9216) + ksum (1152), contiguous

  for (int b = 0; b < 2; ++b) {
    k_qkv<<<dim3(256, 3), 256, 0, stream>>>(x, qkv_w, qkv_b, qkvb, b);
    k_stats<<<dim3(8, 8, 8), 256, 0, stream>>>(qkvb, kvb, ksb, b);
    k_apply<<<2048, 256, 0, stream>>>(qkvb, kvb, ksb, b);
    k_proj<<<4096, 256, 0, stream>>>(qkvb, proj_w, proj_b, x, out, b);
    k_ffn1<<<256, 256, 0, stream>>>(out, ffn1_w, ffn1_b, qkvb, b);
    k_dw<<<16384, 256, 0, stream>>>(qkvb, dw_w, dw_b);
    k_ffn2<<<256, 256, 0, stream>>>(qkvb, ffn2_w, ffn2_b, out, b);
  }
}

// Round 6
// 854.056 us; speedup vs baseline: 2.0926x; 1.3773x over previous
//
#include <hip/hip_runtime.h>
#include <hip/hip_bf16.h>

typedef __hip_bfloat16 bf16;
typedef __attribute__((ext_vector_type(8))) short short8;
typedef __attribute__((ext_vector_type(4))) float floatx4;

#define NPIX 65536   // 256*256

__device__ __forceinline__ float b2f(bf16 v) { return __bfloat162float(v); }
__device__ __forceinline__ bf16 f2b(float v) { return __float2bfloat16(v); }
__device__ __forceinline__ short f2bs(float v) { bf16 t = __float2bfloat16(v); return *(short*)&t; }
__device__ __forceinline__ float gelu_f(float v) {
  return 0.5f * v * (1.f + erff(v * 0.7071067811865476f));
}

// ---- workspace layout (bytes) — total ~24.1 MiB ----
#define OFF_QKV 0u            // bf16 [192, NPIX] per-batch staging
#define OFF_KV  25165824u     // fp32 [2,8,72,8]
#define OFF_KS  25202688u     // fp32 [2,8,72]

__global__ void k_zero(float* __restrict__ p, int n) {
  int i = blockIdx.x * 256 + threadIdx.x;
  if (i < n) p[i] = 0.f;
}

// qkv 1x1 conv + ReLU on q,k. Grid (256, 3): y selects q/k/v section. Thread = pixel.
__global__ __launch_bounds__(256) void k_qkv(const float* __restrict__ x,
                                             const float* __restrict__ qkv_w,
                                             const float* __restrict__ qkv_b,
                                             bf16* __restrict__ qkv, int b) {
  int n = blockIdx.x * 256 + threadIdx.x;
  int sec = blockIdx.y;                      // 0=q, 1=k, 2=v
  const float* xp = x + ((size_t)b << 22) + n;
  float xv[64];
#pragma unroll
  for (int ci = 0; ci < 64; ++ci) xv[ci] = xp[(size_t)ci << 16];
  const float* w = qkv_w + sec * 64 * 64;    // [64][64] slice
  const float* bias = qkv_b + sec * 64;
  bf16* op = qkv + ((size_t)(sec * 64) << 16) + n;
  for (int co = 0; co < 64; ++co) {
    float acc = bias[co];
    const float* wr = w + co * 64;
#pragma unroll
    for (int ci = 0; ci < 64; ++ci) acc = fmaf(xv[ci], wr[ci], acc);
    if (sec < 2) acc = fmaxf(acc, 0.f);
    op[(size_t)co << 16] = f2b(acc);
  }
}

// Attention stats: kv[b,h,d,e] = sum_n k_c(n+off_p) * v_e(n), ksum[b,h,d] = sum_n k.
// Lane = pixel (coalesced); thread accumulates full 9x8 kv tile + 9 ksum in regs.
__global__ __launch_bounds__(256) void k_stats(const bf16* __restrict__ qkv,
                                               float* __restrict__ kv,
                                               float* __restrict__ ksum, int b) {
  int tid = threadIdx.x;
  int chunk = blockIdx.x, c = blockIdx.y, h = blockIdx.z;
  const bf16* kp = qkv + ((size_t)(64 + h * 8 + c) << 16);
  const bf16* vbase = qkv + ((size_t)(128 + h * 8) << 16);
  float acc[9][8];
  float accs[9];
#pragma unroll
  for (int p = 0; p < 9; ++p) {
    accs[p] = 0.f;
#pragma unroll
    for (int e = 0; e < 8; ++e) acc[p][e] = 0.f;
  }
  int n0 = (chunk << 13) + tid;
  for (int i = 0; i < 32; ++i) {
    int n = n0 + (i << 8);
    int y = n >> 8, x = n & 255;
    float v[8];
#pragma unroll
    for (int e = 0; e < 8; ++e) v[e] = b2f(vbase[((size_t)e << 16) + n]);
#pragma unroll
    for (int p = 0; p < 9; ++p) {
      int yy = y + p / 3 - 1, xc = x + (p % 3) - 1;
      float kval = 0.f;
      if ((unsigned)yy < 256u && (unsigned)xc < 256u) kval = b2f(kp[yy * 256 + xc]);
      accs[p] += kval;
#pragma unroll
      for (int e = 0; e < 8; ++e) acc[p][e] = fmaf(kval, v[e], acc[p][e]);
    }
  }
#pragma unroll
  for (int p = 0; p < 9; ++p) {
#pragma unroll
    for (int e = 0; e < 8; ++e)
#pragma unroll
      for (int s = 32; s; s >>= 1) acc[p][e] += __shfl_xor(acc[p][e], s, 64);
#pragma unroll
    for (int s = 32; s; s >>= 1) accs[p] += __shfl_xor(accs[p], s, 64);
  }
  if ((tid & 63) == 0) {
    int dbase = (b * 8 + h) * 72 + c * 9;
#pragma unroll
    for (int p = 0; p < 9; ++p) {
#pragma unroll
      for (int e = 0; e < 8; ++e) atomicAdd(&kv[((dbase + p) << 3) + e], acc[p][e]);
      atomicAdd(&ksum[dbase + p], accs[p]);
    }
  }
}

// o[h*8+e, n] = (sum_d q[n,d]*kv[d,e]) / (sum_d q[n,d]*ksum[d] + eps); o -> v planes.
__global__ __launch_bounds__(256) void k_apply(bf16* __restrict__ qkv,
                                               const float* __restrict__ kv,
                                               const float* __restrict__ ksum, int b) {
  int blk = blockIdx.x;
  int chunk = blk & 255, h = blk >> 8;
  int n = (chunk << 8) + threadIdx.x;
  int y = n >> 8, xx = n & 255;
  const float* kvb = kv + (size_t)((b * 8 + h) * 72) * 8;
  const float* ksb = ksum + (b * 8 + h) * 72;
  float num[8] = {0.f, 0.f, 0.f, 0.f, 0.f, 0.f, 0.f, 0.f};
  float den = 0.f;
  for (int c = 0; c < 8; ++c) {
    const bf16* qp = qkv + ((size_t)(h * 8 + c) << 16);
#pragma unroll
    for (int p = 0; p < 9; ++p) {
      int yy = y + p / 3 - 1, xc = xx + p % 3 - 1;
      float qv = 0.f;
      if ((unsigned)yy < 256u && (unsigned)xc < 256u) qv = b2f(qp[yy * 256 + xc]);
      int d = c * 9 + p;
      den = fmaf(qv, ksb[d], den);
#pragma unroll
      for (int e = 0; e < 8; ++e) num[e] = fmaf(qv, kvb[d * 8 + e], num[e]);
    }
  }
  float inv = 1.f / (den + 1e-6f);
#pragma unroll
  for (int e = 0; e < 8; ++e)
    qkv[((size_t)(128 + h * 8 + e) << 16) + n] = f2b(num[e] * inv);
}

// proj 3x3 conv as implicit GEMM via MFMA 16x16x32 bf16.
// M=64 co, N=128 px (half row), K=576 = 18 steps of (p, ci-half32).
// Block: 256 thr (4 waves); wave w -> co [16w,16w+16); LDS o-tile [3][130][72pad] bf16.
// Grid: dim3(2, 256). Epilogue adds proj_b + residual x, writes fp32 x1 to d_out.
__global__ __launch_bounds__(256) void k_proj_mfma(const bf16* __restrict__ qkv,
                                                   const float* __restrict__ proj_w,
                                                   const float* __restrict__ proj_b,
                                                   const float* __restrict__ x,
                                                   float* __restrict__ out, int b) {
  __shared__ __align__(16) bf16 tile[3 * 130 * 72];
  int tid = threadIdx.x;
  int wv = tid >> 6, ln = tid & 63;
  int half = blockIdx.x, y = blockIdx.y;
  int x0 = half << 7;

  // ---- stage o-tile (v planes 128..191): rows y-1..y+1, x0-1..x0+128, all 64 ci
  for (int pr = wv; pr < 192; pr += 4) {      // pr = dy*64 + ci
    int dy = pr >> 6, ci = pr & 63;
    int gy = y + dy - 1;
    const bf16* src = qkv + ((size_t)(128 + ci) << 16) + gy * 256;
    bool rowok = (unsigned)gy < 256u;
    for (int xl = ln; xl < 130; xl += 64) {
      int gx = x0 - 1 + xl;
      float v = 0.f;
      if (rowok && (unsigned)gx < 256u) v = b2f(src[gx]);
      tile[(dy * 130 + xl) * 72 + ci] = f2b(v);
    }
  }

  // ---- A fragments: w[co][ci][p] -> bf16, 18 steps x 8 vals (overlaps staging)
  int m = ln & 15, quad = ln >> 4;
  int co = wv * 16 + m;
  short8 afrag[18];
#pragma unroll
  for (int s = 0; s < 18; ++s) {
    int p = s >> 1;
    int ci0 = (s & 1) * 32 + quad * 8;
    short8 af;
#pragma unroll
    for (int j = 0; j < 8; ++j)
      af[j] = f2bs(proj_w[(size_t)(co * 64 + ci0 + j) * 9 + p]);
    afrag[s] = af;
  }
  __syncthreads();

  // ---- K-loop: 18 steps x 8 N-tiles
  floatx4 acc[8];
#pragma unroll
  for (int nt = 0; nt < 8; ++nt) acc[nt] = (floatx4){0.f, 0.f, 0.f, 0.f};
  int col = ln & 15;
#pragma unroll
  for (int s = 0; s < 18; ++s) {
    int p = s >> 1;
    int dy = p / 3, dx = p % 3;
    int ci_sub = (s & 1) * 32 + quad * 8;
    int base = (dy * 130 + col + dx) * 72 + ci_sub;
#pragma unroll
    for (int nt = 0; nt < 8; ++nt) {
      short8 bfrag = *(const short8*)&tile[base + nt * 16 * 72];
      acc[nt] = __builtin_amdgcn_mfma_f32_16x16x32_bf16(afrag[s], bfrag, acc[nt], 0, 0, 0);
    }
  }

  // ---- epilogue: out[co_r][y][x] = x + bias + acc   (C/D: col=lane&15, row=quad*4+r)
  float bias4[4];
#pragma unroll
  for (int r = 0; r < 4; ++r) bias4[r] = proj_b[wv * 16 + quad * 4 + r];
#pragma unroll
  for (int nt = 0; nt < 8; ++nt) {
    int gx = x0 + nt * 16 + col;
#pragma unroll
    for (int r = 0; r < 4; ++r) {
      int co_r = wv * 16 + quad * 4 + r;
      size_t idx = ((size_t)(b * 64 + co_r) << 16) + (y << 8) + gx;
      out[idx] = x[idx] + bias4[r] + acc[nt][r];
    }
  }
}

// ffn1: 1x1 conv on x1 (fp32, in d_out) + exact GELU -> h1 in q planes. Thread = pixel.
__global__ __launch_bounds__(256) void k_ffn1(const float* __restrict__ out,
                                              const float* __restrict__ w1,
                                              const float* __restrict__ b1,
                                              bf16* __restrict__ qkv, int b) {
  int n = blockIdx.x * 256 + threadIdx.x;
  float xv[64];
  const float* xp = out + ((size_t)b << 22) + n;
#pragma unroll
  for (int ci = 0; ci < 64; ++ci) xv[ci] = xp[(size_t)ci << 16];
  for (int co = 0; co < 64; ++co) {
    float acc = b1[co];
    const float* wr = w1 + co * 64;
#pragma unroll
    for (int ci = 0; ci < 64; ++ci) acc = fmaf(xv[ci], wr[ci], acc);
    qkv[((size_t)co << 16) + n] = f2b(gelu_f(acc));
  }
}

// depthwise 3x3 + GELU: h1 (q planes) -> h2 (k planes). Thread = element.
__global__ __launch_bounds__(256) void k_dw(bf16* __restrict__ qkv,
                                            const float* __restrict__ dw_w,
                                            const float* __restrict__ dw_b) {
  int gid = blockIdx.x * 256 + threadIdx.x;   // [0, 64*NPIX)
  int n = gid & 65535;
  int c = gid >> 16;
  int y = n >> 8, xx = n & 255;
  const bf16* ip = qkv + ((size_t)c << 16);
  float acc = dw_b[c];
#pragma unroll
  for (int p = 0; p < 9; ++p) {
    int yy = y + p / 3 - 1, xc = xx + p % 3 - 1;
    if ((unsigned)yy < 256u && (unsigned)xc < 256u)
      acc = fmaf(b2f(ip[yy * 256 + xc]), dw_w[c * 9 + p], acc);
  }
  qkv[((size_t)(64 + c) << 16) + n] = f2b(gelu_f(acc));
}

// ffn2: 1x1 conv on h2 (k planes) + residual x1 (d_out, element-wise in place, fp32).
__global__ __launch_bounds__(256) void k_ffn2(const bf16* __restrict__ qkv,
                                              const float* __restrict__ w2,
                                              const float* __restrict__ b2,
                                              float* __restrict__ out, int b) {
  int n = blockIdx.x * 256 + threadIdx.x;
  float xv[64];
  const bf16* xp = qkv + ((size_t)64 << 16) + n;
#pragma unroll
  for (int ci = 0; ci < 64; ++ci) xv[ci] = b2f(xp[(size_t)ci << 16]);
  for (int co = 0; co < 64; ++co) {
    float acc = b2[co];
    const float* wr = w2 + co * 64;
#pragma unroll
    for (int ci = 0; ci < 64; ++ci) acc = fmaf(xv[ci], wr[ci], acc);
    size_t idx = ((size_t)b << 22) + ((size_t)co << 16) + n;
    out[idx] = out[idx] + acc;
  }
}

extern "C" void kernel_launch(void* const* d_in, const int* in_sizes, int n_in,
                              void* d_out, int out_size, void* d_ws, size_t ws_size,
                              hipStream_t stream) {
  const float* x      = (const float*)d_in[0];
  const float* qkv_w  = (const float*)d_in[1];
  const float* qkv_b  = (const float*)d_in[2];
  const float* proj_w = (const float*)d_in[3];
  const float* proj_b = (const float*)d_in[4];
  const float* ffn1_w = (const float*)d_in[5];
  const float* ffn1_b = (const float*)d_in[6];
  const float* dw_w   = (const float*)d_in[7];
  const float* dw_b   = (const float*)d_in[8];
  const float* ffn2_w = (const float*)d_in[9];
  const float* ffn2_b = (const float*)d_in[10];
  float* out = (float*)d_out;

  char* ws = (char*)d_ws;
  bf16*  qkvb = (bf16*)(ws + OFF_QKV);
  float* kvb  = (float*)(ws + OFF_KV);
  float* ksb  = (float*)(ws + OFF_KS);

  k_zero<<<41, 256, 0, stream>>>(kvb, 10368);  // kv (9216) + ksum (1152), contiguous

  for (int b = 0; b < 2; ++b) {
    k_qkv<<<dim3(256, 3), 256, 0, stream>>>(x, qkv_w, qkv_b, qkvb, b);
    k_stats<<<dim3(8, 8, 8), 256, 0, stream>>>(qkvb, kvb, ksb, b);
    k_apply<<<2048, 256, 0, stream>>>(qkvb, kvb, ksb, b);
    k_proj_mfma<<<dim3(2, 256), 256, 0, stream>>>(qkvb, proj_w, proj_b, x, out, b);
    k_ffn1<<<256, 256, 0, stream>>>(out, ffn1_w, ffn1_b, qkvb, b);
    k_dw<<<16384, 256, 0, stream>>>(qkvb, dw_w, dw_b);
    k_ffn2<<<256, 256, 0, stream>>>(qkvb, ffn2_w, ffn2_b, out, b);
  }
}